// Round 10
// baseline (265.344 us; speedup 1.0000x reference)
//
#include <hip/hip_runtime.h>
#include <hip/hip_bf16.h>

#define Bb 8
#define Ll 512
#define Dd 32
#define Nn 64
#define Hh 64
#define G4 256  // 4*H

#define L2E  1.4426950408889634f   // log2(e)
#define L2E2 2.8853900817779268f   // 2*log2(e)

typedef _Float16 h2_t __attribute__((ext_vector_type(2)));

__device__ __forceinline__ float fast_rcp(float x) { return __builtin_amdgcn_rcpf(x); }
// v_exp_f32 computes 2^x directly
__device__ __forceinline__ float fast_exp2(float x) { return __builtin_amdgcn_exp2f(x); }

__device__ __forceinline__ float fdot2(h2_t a, h2_t b, float c) {
#if __has_builtin(__builtin_amdgcn_fdot2)
    return __builtin_amdgcn_fdot2(a, b, c, false);
#else
    return c + (float)a[0] * (float)b[0] + (float)a[1] * (float)b[1];
#endif
}

template<int CTRL>
__device__ __forceinline__ float quad_dpp(float v) {
    return __int_as_float(__builtin_amdgcn_mov_dpp(__float_as_int(v), CTRL, 0xf, 0xf, true));
}
__device__ __forceinline__ float quad_sum(float v) {
    v += quad_dpp<0xB1>(v);   // quad_perm [1,0,3,2]
    v += quad_dpp<0x4E>(v);   // quad_perm [2,3,0,1]
    return v;
}

// ---------------- Kernel 1: exp-space projections ----------------
__global__ __launch_bounds__(256) void k_proj(
    const float* __restrict__ text,
    const float* __restrict__ Wx_w, const float* __restrict__ Wx_b,
    const float* __restrict__ Wxh_w, const float* __restrict__ Wxh_b,
    float* __restrict__ Ex, float* __restrict__ Eh) {
    int idx = blockIdx.x * 256 + threadIdx.x;   // B*L*N
    int n = idx & 63;
    int bl = idx >> 6;
    const float4* tr = (const float4*)(text + bl * Dd);
    const float4* w1 = (const float4*)(Wx_w + n * Dd);
    const float4* w2 = (const float4*)(Wxh_w + n * Dd);
    float a0 = 0.f, a1 = 0.f;
#pragma unroll
    for (int q = 0; q < 8; ++q) {
        float4 t4 = tr[q]; float4 x4 = w1[q]; float4 y4 = w2[q];
        a0 += t4.x * x4.x + t4.y * x4.y + t4.z * x4.z + t4.w * x4.w;
        a1 += t4.x * y4.x + t4.y * y4.y + t4.z * y4.z + t4.w * y4.w;
    }
    Ex[idx] = fast_exp2(L2E2 * (a0 + Wx_b[n]));
    Eh[idx] = fast_exp2(L2E2 * (a1 + Wxh_b[n]));
}

// ---------------- Kernel 2: fused attention + Xatt + Gx ----------------
// DS-pressure cut vs R9: att_w held in 64 VGPRs (broadcast global loads,
// statically indexed), F read as b64 pairs from a float-only LDS array.
// Epilogue pre-scales Gx rows by -L2E (gates i,f,o) / -L2E2 (gate g) so
// k_lstm's activations skip the multiply: sig = rcp(1+exp2(t_scaled)).
__global__ __launch_bounds__(256) void k_attn(
    const float* __restrict__ text,
    const float* __restrict__ Ex, const float* __restrict__ Eh,
    const float* __restrict__ att_w, const float* __restrict__ att_b,
    const float* __restrict__ W_ih, const float* __restrict__ b_ih,
    const float* __restrict__ b_hh, float* __restrict__ Gx) {
    __shared__ float s_eh[64 * 66];    // [j][n] j-major, pad 66
    __shared__ float s_text[32 * 66];  // [d][j] padded 66
    __shared__ float s_f[4 * 64];      // F per (wave-row, n)
    __shared__ float s_A[4 * 64];      // per-wave A chunk
    __shared__ __align__(16) float s_xatt[4][32];  // finished Xatt rows

    int tid = threadIdx.x;
    int bx = blockIdx.x;           // 0..1023
    int b = bx >> 7;               // /128
    int i0 = (bx & 127) << 2;      // *4
    int w = tid >> 6, l = tid & 63;
    int i = i0 + w;

    // att_w -> 64 VGPRs (uniform broadcast loads, statically indexed)
    float r_aw[64];
    {
        const float4* ap = (const float4*)att_w;
#pragma unroll
        for (int q = 0; q < 16; ++q) {
            float4 v = ap[q];
            r_aw[4 * q]     = v.x; r_aw[4 * q + 1] = v.y;
            r_aw[4 * q + 2] = v.z; r_aw[4 * q + 3] = v.w;
        }
    }
    float awsum = 0.f;
#pragma unroll
    for (int n = 0; n < 64; ++n) awsum += r_aw[n];

    // stage F for this block's 4 i-rows
    s_f[w * 64 + l] = Ex[((b * Ll) + i) * Nn + l];
    float zc = awsum + att_b[0];
    __syncthreads();

    float xacc = 0.f;              // lane: d = l&31, half = l>>5
    int d = l & 31, hf = l >> 5;

    for (int jt = 0; jt < 8; ++jt) {
        __syncthreads();
        {   // stage Eh tile j-major [j][n] + text tile [d][j]
            int n = tid & 63; int j4 = tid >> 6;
#pragma unroll
            for (int r = 0; r < 16; ++r) {
                int jl = j4 + r * 4;
                s_eh[jl * 66 + n] = Eh[((b * Ll) + jt * 64 + jl) * Nn + n];
            }
            int dd = tid & 31; int j8 = tid >> 5;
#pragma unroll
            for (int r = 0; r < 8; ++r) {
                int jl = j8 + r * 8;
                s_text[dd * 66 + jl] = text[((b * Ll) + jt * 64 + jl) * Dd + dd];
            }
        }
        __syncthreads();
        float S = 0.f;
        const float* ehrow = &s_eh[l * 66];
        const float* frow = &s_f[w * 64];
#pragma unroll
        for (int n = 0; n < 64; n += 2) {
            float2 E2 = *(const float2*)(ehrow + n);   // ds_read_b64
            float2 F2 = *(const float2*)(frow + n);    // ds_read_b64 (uniform)
            float r0v = fast_rcp(fmaf(E2.x, F2.x, 1.f));
            S = fmaf(r_aw[n], r0v, S);
            float r1v = fast_rcp(fmaf(E2.y, F2.y, 1.f));
            S = fmaf(r_aw[n + 1], r1v, S);
        }
        // A = sigmoid(awsum - 2S + ab)
        float A = fast_rcp(1.f + fast_exp2(-L2E * (zc - 2.f * S)));
        s_A[w * 64 + l] = A;
#pragma unroll
        for (int jj = 0; jj < 32; jj += 2) {
            int j = hf * 32 + jj;
            float2 A2 = *(const float2*)&s_A[w * 64 + j];
            float2 T2 = *(const float2*)&s_text[d * 66 + j];
            xacc = fmaf(A2.x, T2.x, fmaf(A2.y, T2.y, xacc));
        }
    }
    xacc += __shfl_xor(xacc, 32);
    if (l < 32) s_xatt[w][l] = xacc;   // lanes 0..31 hold d = l
    __syncthreads();

    // ---- fused Gx epilogue: thread tid = W_ih row r0 (gate-major) ----
    {
        int r0 = tid;                  // gate-major row 0..255
        float sc = ((r0 >> 6) == 2) ? -L2E2 : -L2E;   // pre-scale for k_lstm
        const float4* wr = (const float4*)(W_ih + r0 * Dd);
        float4 wv[8];
#pragma unroll
        for (int q = 0; q < 8; ++q) wv[q] = wr[q];
        float bias = b_ih[r0] + b_hh[r0];
#pragma unroll
        for (int r = 0; r < 4; ++r) {
            const float4* xr = (const float4*)s_xatt[r];  // LDS broadcast reads
            float acc = bias;
#pragma unroll
            for (int q = 0; q < 8; ++q) {
                float4 x4 = xr[q]; float4 w4 = wv[q];
                acc += x4.x * w4.x + x4.y * w4.y + x4.z * w4.z + x4.w * w4.w;
            }
            Gx[((b * Ll) + i0 + r) * G4 + r0] = sc * acc;
        }
    }
}

// ---------------- Kernel 3: LSTM recurrence, TWO batches per block ----------------
// R5's proven 4-wave structure, but each lane runs two independent chains
// (batches A,B) sharing the same W_hh registers. The ~360 cyc of exposed
// latency per step (LDS round-trip, act chains, barrier) overlaps between
// the two chains via ILP. W_hh pre-scaled by -L2E/-L2E2 at f16-convert;
// Gx arrives pre-scaled from k_attn -> activation = rcp(1+exp2(t)).
__global__ __launch_bounds__(256) void k_lstm(
    const float* __restrict__ Gx, const float* __restrict__ W_hh,
    const float* __restrict__ dense_w, const float* __restrict__ dense_b,
    float* __restrict__ out) {
    __shared__ __align__(16) _Float16 s_h[2][2][64];   // [batch][buf][unit]
    int bA = blockIdx.x * 2, bB = bA + 1;
    int tid = threadIdx.x;
    int w = tid >> 6, l = tid & 63;
    int p = l & 3;                 // h-slice [16p, 16p+16)
    int u = w * 16 + (l >> 2);     // unit

    // wreg[g][q] = half2 of (-L2E{,2}) * W_hh[g*64+u][p*16 + 2q .. +2)
    h2_t wreg[4][8];
#pragma unroll
    for (int g = 0; g < 4; ++g) {
        float sc = (g == 2) ? -L2E2 : -L2E;
        const float4* wp = (const float4*)(W_hh + (g * 64 + u) * 64 + p * 16);
#pragma unroll
        for (int q = 0; q < 4; ++q) {
            float4 v = wp[q];
            wreg[g][2 * q]     = h2_t{(_Float16)(sc * v.x), (_Float16)(sc * v.y)};
            wreg[g][2 * q + 1] = h2_t{(_Float16)(sc * v.z), (_Float16)(sc * v.w)};
        }
    }

    if (tid < 64) { s_h[0][0][tid] = (_Float16)0.f; s_h[1][0][tid] = (_Float16)0.f; }
    float cA = 0.f, cB = 0.f;
    const float* gxA = Gx + (size_t)bA * Ll * G4;
    const float* gxB = Gx + (size_t)bB * Ll * G4;
    int gidx = p * 64 + u;         // gate p, unit u (pre-scaled values)
    float gxa_c = gxA[gidx], gxa_1 = gxA[G4 + gidx];
    float gxb_c = gxB[gidx], gxb_1 = gxB[G4 + gidx];
    __syncthreads();

    int buf = 0;
    for (int t = 0; t < Ll; ++t) {
        int t2 = (t + 2 < Ll) ? (t + 2) : (Ll - 1);
        float gxa_2 = gxA[(size_t)t2 * G4 + gidx];   // dist-2 prefetch
        float gxb_2 = gxB[(size_t)t2 * G4 + gidx];

        union HU { float4 f; h2_t h[4]; };
        HU ha0, ha1, hb0, hb1;
        ha0.f = *(const float4*)(&s_h[0][buf][p * 16]);
        ha1.f = *(const float4*)(&s_h[0][buf][p * 16 + 8]);
        hb0.f = *(const float4*)(&s_h[1][buf][p * 16]);
        hb1.f = *(const float4*)(&s_h[1][buf][p * 16 + 8]);

        float aA0 = (p == 0) ? gxa_c : 0.f;
        float aA1 = (p == 1) ? gxa_c : 0.f;
        float aA2 = (p == 2) ? gxa_c : 0.f;
        float aA3 = (p == 3) ? gxa_c : 0.f;
        float aB0 = (p == 0) ? gxb_c : 0.f;
        float aB1 = (p == 1) ? gxb_c : 0.f;
        float aB2 = (p == 2) ? gxb_c : 0.f;
        float aB3 = (p == 3) ? gxb_c : 0.f;
#pragma unroll
        for (int q = 0; q < 4; ++q) {
            aA0 = fdot2(ha0.h[q], wreg[0][q], aA0);
            aB0 = fdot2(hb0.h[q], wreg[0][q], aB0);
            aA1 = fdot2(ha0.h[q], wreg[1][q], aA1);
            aB1 = fdot2(hb0.h[q], wreg[1][q], aB1);
            aA2 = fdot2(ha0.h[q], wreg[2][q], aA2);
            aB2 = fdot2(hb0.h[q], wreg[2][q], aB2);
            aA3 = fdot2(ha0.h[q], wreg[3][q], aA3);
            aB3 = fdot2(hb0.h[q], wreg[3][q], aB3);
        }
#pragma unroll
        for (int q = 0; q < 4; ++q) {
            aA0 = fdot2(ha1.h[q], wreg[0][q + 4], aA0);
            aB0 = fdot2(hb1.h[q], wreg[0][q + 4], aB0);
            aA1 = fdot2(ha1.h[q], wreg[1][q + 4], aA1);
            aB1 = fdot2(hb1.h[q], wreg[1][q + 4], aB1);
            aA2 = fdot2(ha1.h[q], wreg[2][q + 4], aA2);
            aB2 = fdot2(hb1.h[q], wreg[2][q + 4], aB2);
            aA3 = fdot2(ha1.h[q], wreg[3][q + 4], aA3);
            aB3 = fdot2(hb1.h[q], wreg[3][q + 4], aB3);
        }
        // quad allreduce (both batches)
        float tiA = quad_sum(aA0), tiB = quad_sum(aB0);
        float tfA = quad_sum(aA1), tfB = quad_sum(aB1);
        float tgA = quad_sum(aA2), tgB = quad_sum(aB2);
        float toA = quad_sum(aA3), toB = quad_sum(aB3);

        // activations: t pre-scaled, so sigmoid = rcp(1+exp2(t))
        float giA = fast_rcp(1.f + fast_exp2(tiA));
        float giB = fast_rcp(1.f + fast_exp2(tiB));
        float gfA = fast_rcp(1.f + fast_exp2(tfA));
        float gfB = fast_rcp(1.f + fast_exp2(tfB));
        float ggA = fmaf(2.f, fast_rcp(1.f + fast_exp2(tgA)), -1.f);
        float ggB = fmaf(2.f, fast_rcp(1.f + fast_exp2(tgB)), -1.f);
        float goA = fast_rcp(1.f + fast_exp2(toA));
        float goB = fast_rcp(1.f + fast_exp2(toB));
        cA = fmaf(gfA, cA, giA * ggA);
        cB = fmaf(gfB, cB, giB * ggB);
        float thA = fmaf(2.f, fast_rcp(1.f + fast_exp2(-L2E2 * cA)), -1.f);
        float thB = fmaf(2.f, fast_rcp(1.f + fast_exp2(-L2E2 * cB)), -1.f);
        float hA = goA * thA;
        float hB = goB * thB;
        if (p == 0) {
            s_h[0][buf ^ 1][u] = (_Float16)hA;
            s_h[1][buf ^ 1][u] = (_Float16)hB;
        }
        __syncthreads();
        buf ^= 1;
        gxa_c = gxa_1; gxa_1 = gxa_2;
        gxb_c = gxb_1; gxb_1 = gxb_2;
    }
    // dense heads
    if (tid < 2) {
        float a = dense_b[tid];
        for (int uu = 0; uu < 64; ++uu)
            a += (float)s_h[0][buf][uu] * dense_w[tid * 64 + uu];
        out[bA * 2 + tid] = a;
    } else if (tid >= 64 && tid < 66) {
        int o = tid - 64;
        float a = dense_b[o];
        for (int uu = 0; uu < 64; ++uu)
            a += (float)s_h[1][buf][uu] * dense_w[o * 64 + uu];
        out[bB * 2 + o] = a;
    }
}

extern "C" void kernel_launch(void* const* d_in, const int* in_sizes, int n_in,
                              void* d_out, int out_size, void* d_ws, size_t ws_size,
                              hipStream_t stream) {
    const float* text    = (const float*)d_in[0];
    const float* Wx_w    = (const float*)d_in[1];
    const float* Wx_b    = (const float*)d_in[2];
    const float* Wxh_w   = (const float*)d_in[3];
    const float* Wxh_b   = (const float*)d_in[4];
    const float* att_w   = (const float*)d_in[5];
    const float* att_b   = (const float*)d_in[6];
    const float* W_ih    = (const float*)d_in[7];
    const float* W_hh    = (const float*)d_in[8];
    const float* b_ih    = (const float*)d_in[9];
    const float* b_hh    = (const float*)d_in[10];
    const float* dense_w = (const float*)d_in[11];
    const float* dense_b = (const float*)d_in[12];

    float* ws   = (float*)d_ws;
    float* Ex   = ws;                 // 8*512*64   = 262144
    float* Eh   = ws + 262144;        // 262144
    float* Gx   = ws + 655360;        // 8*512*256  = 1048576
    float* out  = (float*)d_out;

    hipLaunchKernelGGL(k_proj, dim3((Bb * Ll * Nn) / 256), dim3(256), 0, stream,
                       text, Wx_w, Wx_b, Wxh_w, Wxh_b, Ex, Eh);
    hipLaunchKernelGGL(k_attn, dim3(Bb * (Ll / 4)), dim3(256), 0, stream,
                       text, Ex, Eh, att_w, att_b, W_ih, b_ih, b_hh, Gx);
    hipLaunchKernelGGL(k_lstm, dim3(Bb / 2), dim3(256), 0, stream,
                       Gx, W_hh, dense_w, dense_b, out);
}

// Round 11
// 192.057 us; speedup vs baseline: 1.3816x; 1.3816x over previous
//
#include <hip/hip_runtime.h>
#include <hip/hip_bf16.h>

#define Bb 8
#define Ll 512
#define Dd 32
#define Nn 64
#define Hh 64
#define G4 256  // 4*H

#define L2E  1.4426950408889634f   // log2(e)
#define L2E2 2.8853900817779268f   // 2*log2(e)

typedef _Float16 h2_t __attribute__((ext_vector_type(2)));

__device__ __forceinline__ float fast_rcp(float x) { return __builtin_amdgcn_rcpf(x); }
// v_exp_f32 computes 2^x directly
__device__ __forceinline__ float fast_exp2(float x) { return __builtin_amdgcn_exp2f(x); }

// sigmoid(x) = rcp(1+exp2(-x*log2e)); saturates gracefully, no clamps
__device__ __forceinline__ float sig2(float x) {
    return fast_rcp(1.f + fast_exp2(-L2E * x));
}
// tanh(x) = 2*sigmoid(2x)-1
__device__ __forceinline__ float tanh2(float x) {
    return fmaf(2.f, fast_rcp(1.f + fast_exp2(-L2E2 * x)), -1.f);
}

__device__ __forceinline__ float fdot2(h2_t a, h2_t b, float c) {
#if __has_builtin(__builtin_amdgcn_fdot2)
    return __builtin_amdgcn_fdot2(a, b, c, false);
#else
    return c + (float)a[0] * (float)b[0] + (float)a[1] * (float)b[1];
#endif
}

template<int CTRL>
__device__ __forceinline__ float quad_dpp(float v) {
    return __int_as_float(__builtin_amdgcn_mov_dpp(__float_as_int(v), CTRL, 0xf, 0xf, true));
}
__device__ __forceinline__ float quad_sum(float v) {
    v += quad_dpp<0xB1>(v);   // quad_perm [1,0,3,2]
    v += quad_dpp<0x4E>(v);   // quad_perm [2,3,0,1]
    return v;
}

// ---------------- Kernel 1: exp-space projections ----------------
__global__ __launch_bounds__(256) void k_proj(
    const float* __restrict__ text,
    const float* __restrict__ Wx_w, const float* __restrict__ Wx_b,
    const float* __restrict__ Wxh_w, const float* __restrict__ Wxh_b,
    float* __restrict__ Ex, float* __restrict__ Eh) {
    int idx = blockIdx.x * 256 + threadIdx.x;   // B*L*N
    int n = idx & 63;
    int bl = idx >> 6;
    const float4* tr = (const float4*)(text + bl * Dd);
    const float4* w1 = (const float4*)(Wx_w + n * Dd);
    const float4* w2 = (const float4*)(Wxh_w + n * Dd);
    float a0 = 0.f, a1 = 0.f;
#pragma unroll
    for (int q = 0; q < 8; ++q) {
        float4 t4 = tr[q]; float4 x4 = w1[q]; float4 y4 = w2[q];
        a0 += t4.x * x4.x + t4.y * x4.y + t4.z * x4.z + t4.w * x4.w;
        a1 += t4.x * y4.x + t4.y * y4.y + t4.z * y4.z + t4.w * y4.w;
    }
    Ex[idx] = fast_exp2(L2E2 * (a0 + Wx_b[n]));
    Eh[idx] = fast_exp2(L2E2 * (a1 + Wxh_b[n]));
}

// ---------------- Kernel 2: fused attention + Xatt + Gx ----------------
// tanh(wxh+wx) = 1 - 2*rcp(E*F+1); z = awsum - 2*sum_n aw_n*rcp(E_n*F_n+1).
// Inner loops quartered: E as b128 (4 n / read, row stride 68 for 16B
// alignment + balanced bank quads), F as uniform-broadcast b128, A.text
// as b128 pairs. att_w in 64 VGPRs. Gx written UNSCALED, gate-major rows.
__global__ __launch_bounds__(256) void k_attn(
    const float* __restrict__ text,
    const float* __restrict__ Ex, const float* __restrict__ Eh,
    const float* __restrict__ att_w, const float* __restrict__ att_b,
    const float* __restrict__ W_ih, const float* __restrict__ b_ih,
    const float* __restrict__ b_hh, float* __restrict__ Gx) {
    __shared__ float s_eh[64 * 68];    // [j][n] j-major, stride 68 (16B-aligned rows)
    __shared__ float s_text[32 * 68];  // [d][j] stride 68
    __shared__ float s_f[4 * 64];      // F per (wave-row, n)
    __shared__ float s_A[4 * 64];      // per-wave A chunk
    __shared__ __align__(16) float s_xatt[4][32];  // finished Xatt rows

    int tid = threadIdx.x;
    int bx = blockIdx.x;           // 0..1023
    int b = bx >> 7;               // /128
    int i0 = (bx & 127) << 2;      // *4
    int w = tid >> 6, l = tid & 63;
    int i = i0 + w;

    // att_w -> 64 VGPRs (uniform broadcast loads, statically indexed)
    float r_aw[64];
    {
        const float4* ap = (const float4*)att_w;
#pragma unroll
        for (int q = 0; q < 16; ++q) {
            float4 v = ap[q];
            r_aw[4 * q]     = v.x; r_aw[4 * q + 1] = v.y;
            r_aw[4 * q + 2] = v.z; r_aw[4 * q + 3] = v.w;
        }
    }
    float awsum = 0.f;
#pragma unroll
    for (int n = 0; n < 64; ++n) awsum += r_aw[n];

    // stage F for this block's 4 i-rows
    s_f[w * 64 + l] = Ex[((b * Ll) + i) * Nn + l];
    float zc = awsum + att_b[0];
    __syncthreads();

    float xacc = 0.f;              // lane: d = l&31, half = l>>5
    int d = l & 31, hf = l >> 5;

    for (int jt = 0; jt < 8; ++jt) {
        __syncthreads();
        {   // stage Eh tile j-major [j][n] + text tile [d][j]
            int n = tid & 63; int j4 = tid >> 6;
#pragma unroll
            for (int r = 0; r < 16; ++r) {
                int jl = j4 + r * 4;
                s_eh[jl * 68 + n] = Eh[((b * Ll) + jt * 64 + jl) * Nn + n];
            }
            int dd = tid & 31; int j8 = tid >> 5;
#pragma unroll
            for (int r = 0; r < 8; ++r) {
                int jl = j8 + r * 8;
                s_text[dd * 68 + jl] = text[((b * Ll) + jt * 64 + jl) * Dd + dd];
            }
        }
        __syncthreads();
        float S = 0.f;
        const float* ehrow = &s_eh[l * 68];
        const float* frow = &s_f[w * 64];
#pragma unroll
        for (int n = 0; n < 64; n += 4) {
            float4 E4 = *(const float4*)(ehrow + n);   // ds_read_b128, balanced banks
            float4 F4 = *(const float4*)(frow + n);    // b128 uniform broadcast
            float r0v = fast_rcp(fmaf(E4.x, F4.x, 1.f));
            S = fmaf(r_aw[n], r0v, S);
            float r1v = fast_rcp(fmaf(E4.y, F4.y, 1.f));
            S = fmaf(r_aw[n + 1], r1v, S);
            float r2v = fast_rcp(fmaf(E4.z, F4.z, 1.f));
            S = fmaf(r_aw[n + 2], r2v, S);
            float r3v = fast_rcp(fmaf(E4.w, F4.w, 1.f));
            S = fmaf(r_aw[n + 3], r3v, S);
        }
        // A = sigmoid(awsum - 2S + ab)
        float A = fast_rcp(1.f + fast_exp2(-L2E * (zc - 2.f * S)));
        s_A[w * 64 + l] = A;
#pragma unroll
        for (int jj = 0; jj < 32; jj += 4) {
            int j = hf * 32 + jj;
            float4 A4 = *(const float4*)&s_A[w * 64 + j];     // b128 (broadcast per half)
            float4 T4 = *(const float4*)&s_text[d * 68 + j];  // b128
            xacc = fmaf(A4.x, T4.x, xacc);
            xacc = fmaf(A4.y, T4.y, xacc);
            xacc = fmaf(A4.z, T4.z, xacc);
            xacc = fmaf(A4.w, T4.w, xacc);
        }
    }
    xacc += __shfl_xor(xacc, 32);
    if (l < 32) s_xatt[w][l] = xacc;   // lanes 0..31 hold d = l
    __syncthreads();

    // ---- fused Gx epilogue: thread tid = W_ih row r0 (gate-major) ----
    {
        int r0 = tid;                  // gate-major row 0..255
        const float4* wr = (const float4*)(W_ih + r0 * Dd);
        float4 wv[8];
#pragma unroll
        for (int q = 0; q < 8; ++q) wv[q] = wr[q];
        float bias = b_ih[r0] + b_hh[r0];
#pragma unroll
        for (int r = 0; r < 4; ++r) {
            const float4* xr = (const float4*)s_xatt[r];  // LDS broadcast reads
            float acc = bias;
#pragma unroll
            for (int q = 0; q < 8; ++q) {
                float4 x4 = xr[q]; float4 w4 = wv[q];
                acc += x4.x * w4.x + x4.y * w4.y + x4.z * w4.z + x4.w * w4.w;
            }
            Gx[((b * Ll) + i0 + r) * G4 + r0] = acc;
        }
    }
}

// ---------------- Kernel 3: LSTM recurrence (one block per batch) ----------------
// PROVEN 150-us structure (R5), exact revert + one micro: the dist-2 Gx
// prefetch address is a uniform pointer bump (no per-step 64-bit mul).
// 4 waves. Lane: part p = l&3 (16-elem h slice), unit u = w*16 + (l>>2).
// h in LDS f16; W_hh half2 in VGPRs; v_dot2 partials; quad DPP allreduce;
// lean exp2/rcp activations. 1 barrier/step, double-buffered h.
__global__ __launch_bounds__(256) void k_lstm(
    const float* __restrict__ Gx, const float* __restrict__ W_hh,
    const float* __restrict__ dense_w, const float* __restrict__ dense_b,
    float* __restrict__ out) {
    __shared__ __align__(16) _Float16 s_h[2][64];
    int b = blockIdx.x;
    int tid = threadIdx.x;
    int w = tid >> 6, l = tid & 63;
    int p = l & 3;                 // h-slice [16p, 16p+16)
    int u = w * 16 + (l >> 2);     // unit

    // wreg[g][q] = half2 of W_hh[g*64+u][p*16 + 2q .. +2)
    h2_t wreg[4][8];
#pragma unroll
    for (int g = 0; g < 4; ++g) {
        const float4* wp = (const float4*)(W_hh + (g * 64 + u) * 64 + p * 16);
#pragma unroll
        for (int q = 0; q < 4; ++q) {
            float4 v = wp[q];
            wreg[g][2 * q]     = h2_t{(_Float16)v.x, (_Float16)v.y};
            wreg[g][2 * q + 1] = h2_t{(_Float16)v.z, (_Float16)v.w};
        }
    }

    if (tid < 64) s_h[0][tid] = (_Float16)0.f;
    float c = 0.f;
    const float* gxb = Gx + (size_t)b * Ll * G4;
    int gidx = p * 64 + u;         // this lane's gx element (gate p, unit u)
    float gx_cur = gxb[gidx];             // t = 0
    float gx_n1  = gxb[G4 + gidx];        // t = 1
    const float* gp2 = gxb + 2 * G4 + gidx;   // walks t+2, clamped at 511
    __syncthreads();

    int buf = 0;
    for (int t = 0; t < Ll; ++t) {
        float gx_n2 = *gp2;                     // dist-2 prefetch
        if (t < Ll - 3) gp2 += G4;              // uniform pointer bump w/ clamp

        // read this lane's 16-half slice of h as 2 x b128
        union { float4 f; h2_t h[4]; } u0, u1;
        u0.f = *(const float4*)(&s_h[buf][p * 16]);
        u1.f = *(const float4*)(&s_h[buf][p * 16 + 8]);

        float a0 = (p == 0) ? gx_cur : 0.f;
        float a1 = (p == 1) ? gx_cur : 0.f;
        float a2 = (p == 2) ? gx_cur : 0.f;
        float a3 = (p == 3) ? gx_cur : 0.f;
#pragma unroll
        for (int q = 0; q < 4; ++q) {
            a0 = fdot2(u0.h[q], wreg[0][q], a0);
            a1 = fdot2(u0.h[q], wreg[1][q], a1);
            a2 = fdot2(u0.h[q], wreg[2][q], a2);
            a3 = fdot2(u0.h[q], wreg[3][q], a3);
        }
#pragma unroll
        for (int q = 0; q < 4; ++q) {
            a0 = fdot2(u1.h[q], wreg[0][q + 4], a0);
            a1 = fdot2(u1.h[q], wreg[1][q + 4], a1);
            a2 = fdot2(u1.h[q], wreg[2][q + 4], a2);
            a3 = fdot2(u1.h[q], wreg[3][q + 4], a3);
        }
        // quad reduce: every lane gets all four gate totals (bit-identical)
        float ti = quad_sum(a0);
        float tf = quad_sum(a1);
        float tg = quad_sum(a2);
        float to = quad_sum(a3);

        float gi = sig2(ti);
        float gf = sig2(tf);
        float gg = tanh2(tg);
        float go = sig2(to);
        c = fmaf(gf, c, gi * gg);
        float hh = go * tanh2(c);
        if (p == 0) s_h[buf ^ 1][u] = (_Float16)hh;
        __syncthreads();
        buf ^= 1;
        gx_cur = gx_n1;
        gx_n1 = gx_n2;
    }
    if (tid == 0) {   // dense head for this batch row
        float a0 = dense_b[0], a1 = dense_b[1];
        for (int uu = 0; uu < 64; ++uu) {
            float hv = (float)s_h[buf][uu];
            a0 += hv * dense_w[uu];
            a1 += hv * dense_w[64 + uu];
        }
        out[b * 2 + 0] = a0;
        out[b * 2 + 1] = a1;
    }
}

extern "C" void kernel_launch(void* const* d_in, const int* in_sizes, int n_in,
                              void* d_out, int out_size, void* d_ws, size_t ws_size,
                              hipStream_t stream) {
    const float* text    = (const float*)d_in[0];
    const float* Wx_w    = (const float*)d_in[1];
    const float* Wx_b    = (const float*)d_in[2];
    const float* Wxh_w   = (const float*)d_in[3];
    const float* Wxh_b   = (const float*)d_in[4];
    const float* att_w   = (const float*)d_in[5];
    const float* att_b   = (const float*)d_in[6];
    const float* W_ih    = (const float*)d_in[7];
    const float* W_hh    = (const float*)d_in[8];
    const float* b_ih    = (const float*)d_in[9];
    const float* b_hh    = (const float*)d_in[10];
    const float* dense_w = (const float*)d_in[11];
    const float* dense_b = (const float*)d_in[12];

    float* ws   = (float*)d_ws;
    float* Ex   = ws;                 // 8*512*64   = 262144
    float* Eh   = ws + 262144;        // 262144
    float* Gx   = ws + 655360;        // 8*512*256  = 1048576
    float* out  = (float*)d_out;

    hipLaunchKernelGGL(k_proj, dim3((Bb * Ll * Nn) / 256), dim3(256), 0, stream,
                       text, Wx_w, Wx_b, Wxh_w, Wxh_b, Ex, Eh);
    hipLaunchKernelGGL(k_attn, dim3(Bb * (Ll / 4)), dim3(256), 0, stream,
                       text, Ex, Eh, att_w, att_b, W_ih, b_ih, b_hh, Gx);
    hipLaunchKernelGGL(k_lstm, dim3(Bb), dim3(256), 0, stream,
                       Gx, W_hh, dense_w, dense_b, out);
}